// Round 10
// baseline (250.655 us; speedup 1.0000x reference)
//
#include <hip/hip_runtime.h>
#include <hip/hip_bf16.h>
#include <stdint.h>

typedef __attribute__((ext_vector_type(4))) float f32x4;
typedef __attribute__((ext_vector_type(8))) short s16x8;
typedef __attribute__((ext_vector_type(4))) unsigned short u16x4;
typedef __attribute__((ext_vector_type(4))) int i32x4;

#define B2T 16384
#define BH 8192
#define DIN 1024
#define DD1 512
#define DIMS 256
#define NC 40
#define CAPS 2048

__device__ __forceinline__ unsigned short f2b(float f) {
  unsigned int u = __builtin_bit_cast(unsigned int, f);
  u += 0x7FFFu + ((u >> 16) & 1u);
  return (unsigned short)(u >> 16);
}

// ---------------- prep_all: fused Weff tiles / beff / W3T / W4T / stat-zero -----------------
__global__ __launch_bounds__(256) void prep_all(const float* __restrict__ W1,
                                                const float* __restrict__ W2,
                                                const float* __restrict__ b1,
                                                const float* __restrict__ b2,
                                                const float* __restrict__ W3,
                                                const float* __restrict__ W4,
                                                unsigned short* __restrict__ WeffT,
                                                float* __restrict__ beff,
                                                unsigned short* __restrict__ W3T,
                                                unsigned short* __restrict__ W4T,
                                                float* __restrict__ statz) {
  __shared__ float W1s[32][36];
  __shared__ float W2sT[32][36];
  int b = blockIdx.x, t = threadIdx.x;
  if (b < 256) {
    int k0 = (b & 31) * 32, n0 = (b >> 5) * 32;
    int nn = t & 31, kq = t >> 5;  // kq in 0..7
    f32x4 acc = (f32x4){0.f, 0.f, 0.f, 0.f};
    for (int j0 = 0; j0 < DD1; j0 += 32) {
#pragma unroll
      for (int i = 0; i < 4; ++i) {
        int idx = t + 256 * i;
        int kk = idx >> 5, jj = idx & 31;
        W1s[kk][jj] = W1[(size_t)(k0 + kk) * DD1 + j0 + jj];
        W2sT[jj][kk] = W2[(size_t)(j0 + kk) * DIMS + n0 + jj];
      }
      __syncthreads();
#pragma unroll
      for (int jj4 = 0; jj4 < 8; ++jj4) {
        f32x4 w2 = *(const f32x4*)&W2sT[nn][jj4 * 4];
        f32x4 w1_0 = *(const f32x4*)&W1s[kq * 4 + 0][jj4 * 4];
        f32x4 w1_1 = *(const f32x4*)&W1s[kq * 4 + 1][jj4 * 4];
        f32x4 w1_2 = *(const f32x4*)&W1s[kq * 4 + 2][jj4 * 4];
        f32x4 w1_3 = *(const f32x4*)&W1s[kq * 4 + 3][jj4 * 4];
        acc[0] += w1_0[0] * w2[0] + w1_0[1] * w2[1] + w1_0[2] * w2[2] + w1_0[3] * w2[3];
        acc[1] += w1_1[0] * w2[0] + w1_1[1] * w2[1] + w1_1[2] * w2[2] + w1_1[3] * w2[3];
        acc[2] += w1_2[0] * w2[0] + w1_2[1] * w2[1] + w1_2[2] * w2[2] + w1_2[3] * w2[3];
        acc[3] += w1_3[0] * w2[0] + w1_3[1] * w2[1] + w1_3[2] * w2[2] + w1_3[3] * w2[3];
      }
      __syncthreads();
    }
    u16x4 pk = {f2b(acc[0]), f2b(acc[1]), f2b(acc[2]), f2b(acc[3])};
    *(u16x4*)(WeffT + (size_t)(n0 + nn) * DIN + k0 + kq * 4) = pk;
  } else if (b == 256) {
    float a0 = 0.f, a1 = 0.f, a2 = 0.f, a3 = 0.f, a4 = 0.f, a5 = 0.f, a6 = 0.f, a7 = 0.f;
    for (int j = 0; j < DD1; j += 8) {
      a0 += b1[j + 0] * W2[(size_t)(j + 0) * DIMS + t];
      a1 += b1[j + 1] * W2[(size_t)(j + 1) * DIMS + t];
      a2 += b1[j + 2] * W2[(size_t)(j + 2) * DIMS + t];
      a3 += b1[j + 3] * W2[(size_t)(j + 3) * DIMS + t];
      a4 += b1[j + 4] * W2[(size_t)(j + 4) * DIMS + t];
      a5 += b1[j + 5] * W2[(size_t)(j + 5) * DIMS + t];
      a6 += b1[j + 6] * W2[(size_t)(j + 6) * DIMS + t];
      a7 += b1[j + 7] * W2[(size_t)(j + 7) * DIMS + t];
    }
    beff[t] = b2[t] + (((a0 + a1) + (a2 + a3)) + ((a4 + a5) + (a6 + a7)));
  } else if (b < 577) {
    int idx = (b - 257) * 256 + t;
    int n = idx / 320, k = idx - n * 320;
    float v = (k < 296) ? W3[(size_t)k * 256 + n] : 0.0f;
    W3T[(size_t)n * 320 + k] = f2b(v);
  } else if (b < 641) {
    int idx = (b - 577) * 256 + t;
    int n = idx >> 8, k = idx & 255;
    W4T[(size_t)n * 256 + k] = f2b(W4[(size_t)k * 64 + n]);
  } else {
    for (int i = t; i < 640; i += 256) statz[i] = 0.0f;
  }
}

// ---------------- barrier-free MFMA GEMM: A staged whole in LDS, B streamed from L2 ---------
// AMODE: 0=A fp32, 1=A bf16, 2=A fp32 + BN1 + ReLU (LDS table)
// EPI:   1=rownorm+uf-bf16 (CW=4), 2/3=store+bnstat
// LDS A layout: fragment-linear, frag[k8*AR + row] (16 B each) -> 2-way banks on read (free)
template <int AMODE, int NB, int MI, int CW, int EPI, int K>
__global__ __launch_bounds__(256) void gemm_core(
    const void* __restrict__ Aptr, int lda, const unsigned short* __restrict__ BT,
    const float* __restrict__ bias, float* __restrict__ C, int ldc,
    float* __restrict__ sums, float* __restrict__ ssqs,
    const float* __restrict__ bnsum, const float* __restrict__ bnssq,
    const float* __restrict__ bng, const float* __restrict__ bnbe,
    unsigned short* __restrict__ uf) {
  constexpr int AR = (4 / CW) * MI * 16;   // rows per block
  constexpr int NFRAG = AR * K / 8;        // 16B frags in LDS
  constexpr int CHT = NFRAG / 256;         // staging chunks per thread
  constexpr int ROWB = (AR == 64) ? 6 : 5; // log2(AR)
  __shared__ s16x8 A_s[NFRAG];
  __shared__ float rs[4][AR];
  __shared__ float bsc_s[(AMODE == 2) ? 256 : 1];
  __shared__ float bsh_s[(AMODE == 2) ? 256 : 1];
  int t = threadIdx.x;
  int m0 = blockIdx.x * AR;
  int w = t >> 6, lane = t & 63, q = lane >> 4, ln = lane & 15;
  f32x4 acc[MI][4];
#pragma unroll
  for (int mi = 0; mi < MI; ++mi)
#pragma unroll
    for (int ni = 0; ni < 4; ++ni) acc[mi][ni] = (f32x4){0.f, 0.f, 0.f, 0.f};

  if constexpr (AMODE == 2) {
    float mu = bnsum[t] * (1.0f / 8192.0f);
    float var = bnssq[t] * (1.0f / 8192.0f) - mu * mu;
    float sc = bng[t] * rsqrtf(var + 1e-5f);
    bsc_s[t] = sc;
    bsh_s[t] = bnbe[t] - mu * sc;
    __syncthreads();
  }

  // ---- stage ALL of A into LDS once (frag-linear) ----
#pragma unroll
  for (int i = 0; i < CHT; ++i) {
    int ch = t + 256 * i;
    int row = (ch >> 2) & (AR - 1);
    int k8 = (ch & 3) | ((ch >> (2 + ROWB)) << 2);  // global k / 8
    if constexpr (AMODE == 1) {
      const unsigned short* A = (const unsigned short*)Aptr;
      A_s[k8 * AR + row] = *(const s16x8*)(A + (size_t)(m0 + row) * lda + k8 * 8);
    } else {
      const float* A = (const float*)Aptr;
      const f32x4* src = (const f32x4*)(A + (size_t)(m0 + row) * lda + k8 * 8);
      f32x4 v0 = src[0], v1 = src[1];
      if constexpr (AMODE == 2) {
        float vv[8] = {v0[0], v0[1], v0[2], v0[3], v1[0], v1[1], v1[2], v1[3]};
#pragma unroll
        for (int j = 0; j < 8; ++j) {
          int f = k8 * 8 + j;
          vv[j] = fmaxf(vv[j] * bsc_s[f] + bsh_s[f], 0.0f);
        }
        v0 = (f32x4){vv[0], vv[1], vv[2], vv[3]};
        v1 = (f32x4){vv[4], vv[5], vv[6], vv[7]};
      }
      s16x8 p;
      p[0] = (short)f2b(v0[0]); p[1] = (short)f2b(v0[1]);
      p[2] = (short)f2b(v0[2]); p[3] = (short)f2b(v0[3]);
      p[4] = (short)f2b(v1[0]); p[5] = (short)f2b(v1[1]);
      p[6] = (short)f2b(v1[2]); p[7] = (short)f2b(v1[3]);
      A_s[k8 * AR + row] = p;
    }
  }
  __syncthreads();

  // ---- barrier-free K-loop: A frags from LDS, B frags from global (L2-resident) ----
  int ab = (w / CW) * MI * 16;
  int nb0 = (w % CW) * 64;
  const unsigned short* Bb[4];
#pragma unroll
  for (int ni = 0; ni < 4; ++ni)
    Bb[ni] = BT + (size_t)(nb0 + ni * 16 + ln) * K + q * 8;
#pragma unroll 4
  for (int s = 0; s < K / 32; ++s) {
    s16x8 af[MI];
#pragma unroll
    for (int mi = 0; mi < MI; ++mi)
      af[mi] = A_s[(4 * s + q) * AR + ab + mi * 16 + ln];
#pragma unroll
    for (int ni = 0; ni < 4; ++ni) {
      s16x8 bfr = *(const s16x8*)(Bb[ni] + s * 32);
#pragma unroll
      for (int mi = 0; mi < MI; ++mi)
        acc[mi][ni] = __builtin_amdgcn_mfma_f32_16x16x32_bf16(af[mi], bfr, acc[mi][ni], 0, 0, 0);
    }
  }

  float v[MI][4][4];
#pragma unroll
  for (int mi = 0; mi < MI; ++mi)
#pragma unroll
    for (int ni = 0; ni < 4; ++ni) {
      float bv = bias[(w % CW) * 64 + ni * 16 + ln];
#pragma unroll
      for (int r = 0; r < 4; ++r) v[mi][ni][r] = acc[mi][ni][r] + bv;
    }

  if constexpr (EPI == 1) {
    float p[MI][4];
#pragma unroll
    for (int mi = 0; mi < MI; ++mi)
#pragma unroll
      for (int r = 0; r < 4; ++r) {
        float s = v[mi][0][r] * v[mi][0][r] + v[mi][1][r] * v[mi][1][r] +
                  v[mi][2][r] * v[mi][2][r] + v[mi][3][r] * v[mi][3][r];
        s += __shfl_xor(s, 1); s += __shfl_xor(s, 2);
        s += __shfl_xor(s, 4); s += __shfl_xor(s, 8);
        p[mi][r] = s;
      }
    if (ln == 0) {
#pragma unroll
      for (int mi = 0; mi < MI; ++mi)
#pragma unroll
        for (int r = 0; r < 4; ++r) rs[w][mi * 16 + q * 4 + r] = p[mi][r];
    }
    __syncthreads();
    if (t < AR) rs[0][t] = rsqrtf(rs[0][t] + rs[1][t] + rs[2][t] + rs[3][t]);
    __syncthreads();
#pragma unroll
    for (int mi = 0; mi < MI; ++mi)
#pragma unroll
      for (int r = 0; r < 4; ++r) {
        int rib = mi * 16 + q * 4 + r;
        float inv = rs[0][rib];
        int grow = m0 + rib;
#pragma unroll
        for (int ni = 0; ni < 4; ++ni) {
          int col = w * 64 + ni * 16 + ln;
          float nv = v[mi][ni][r] * inv;
          C[(size_t)grow * ldc + col] = nv;
          if (grow >= BH) uf[(size_t)(grow - BH) * 320 + col] = f2b(nv);
        }
      }
  } else {
#pragma unroll
    for (int mi = 0; mi < MI; ++mi)
#pragma unroll
      for (int ni = 0; ni < 4; ++ni)
#pragma unroll
        for (int r = 0; r < 4; ++r) {
          int grow = m0 + (w / CW) * MI * 16 + mi * 16 + q * 4 + r;
          int col = (w % CW) * 64 + ni * 16 + ln;
          C[(size_t)grow * ldc + col] = v[mi][ni][r];
        }
    if constexpr (EPI == 2 || EPI == 3) {
#pragma unroll
      for (int ni = 0; ni < 4; ++ni) {
        float s = 0.f, s2 = 0.f;
#pragma unroll
        for (int mi = 0; mi < MI; ++mi)
#pragma unroll
          for (int r = 0; r < 4; ++r) {
            float x = v[mi][ni][r];
            s += x; s2 += x * x;
          }
        s += __shfl_xor(s, 16); s += __shfl_xor(s, 32);
        s2 += __shfl_xor(s2, 16); s2 += __shfl_xor(s2, 32);
        if (q == 0) {
          int col = (w % CW) * 64 + ni * 16 + ln;
          atomicAdd(&sums[col], s);
          atomicAdd(&ssqs[col], s2);
        }
      }
    }
  }
}

// ---------------- memory-bank EMA scan, closed form (single kernel, 40 blocks) --------------
__global__ __launch_bounds__(256) void bank_kernel(const int* __restrict__ llabel,
                                                   const float* __restrict__ Hn,
                                                   const float* __restrict__ mbank0,
                                                   const float* __restrict__ start0,
                                                   float* __restrict__ mbank_out,
                                                   float* __restrict__ msq) {
  __shared__ i32x4 lab4[BH / 4];  // 32 KB
  __shared__ int idx_s[CAPS];     // 8 KB
  __shared__ int wcnt[4];
  __shared__ float red[4];
  int t = threadIdx.x, c = blockIdx.x;
  int w = t >> 6, lane = t & 63;

  for (int i = t; i < BH / 4; i += 256) lab4[i] = ((const i32x4*)llabel)[i];
  __syncthreads();
  const int* lab_s = (const int*)lab4;

  int base0 = w * (BH / 4);
  int cnt = 0;
  for (int b = 0; b < BH / 4; b += 64)
    cnt += (int)__popcll(__ballot(lab_s[base0 + b + lane] == c));
  if (lane == 0) wcnt[w] = cnt;
  __syncthreads();
  int off = 0;
#pragma unroll
  for (int i = 0; i < 4; ++i)
    if (i < w) off += wcnt[i];
  int Ktot = wcnt[0] + wcnt[1] + wcnt[2] + wcnt[3];

  int running = off;
  for (int b = 0; b < BH / 4; b += 64) {
    bool hit = lab_s[base0 + b + lane] == c;
    unsigned long long mk = __ballot(hit);
    if (hit) {
      int pos = running + (int)__popcll(mk & ((1ull << lane) - 1ull));
      if (pos < CAPS) idx_s[pos] = base0 + b + lane;
    }
    running += (int)__popcll(mk);
  }
  __syncthreads();
  int K = Ktot < CAPS ? Ktot : CAPS;

  const float l09 = -0.15200309344504997f;  // log2(0.9)
  bool fresh = (start0[c] == 0.0f);
  float out;
  if (K == 0) {
    out = mbank0[(size_t)c * DIMS + t];
  } else {
    float a0 = 0.f, a1 = 0.f, a2 = 0.f, a3 = 0.f, a4 = 0.f, a5 = 0.f, a6 = 0.f, a7 = 0.f;
    float w0fold = fresh ? exp2f((float)K * l09) : 0.f;
    int m = 0;
    for (; m + 8 <= K; m += 8) {
      float e = (float)(K - 1 - m);
      float wa = 0.1f * exp2f(e * l09) + (m == 0 ? w0fold : 0.f);
      a0 += wa * Hn[(size_t)idx_s[m + 0] * DIMS + t];
      a1 += 0.1f * exp2f((e - 1.f) * l09) * Hn[(size_t)idx_s[m + 1] * DIMS + t];
      a2 += 0.1f * exp2f((e - 2.f) * l09) * Hn[(size_t)idx_s[m + 2] * DIMS + t];
      a3 += 0.1f * exp2f((e - 3.f) * l09) * Hn[(size_t)idx_s[m + 3] * DIMS + t];
      a4 += 0.1f * exp2f((e - 4.f) * l09) * Hn[(size_t)idx_s[m + 4] * DIMS + t];
      a5 += 0.1f * exp2f((e - 5.f) * l09) * Hn[(size_t)idx_s[m + 5] * DIMS + t];
      a6 += 0.1f * exp2f((e - 6.f) * l09) * Hn[(size_t)idx_s[m + 6] * DIMS + t];
      a7 += 0.1f * exp2f((e - 7.f) * l09) * Hn[(size_t)idx_s[m + 7] * DIMS + t];
    }
    for (; m < K; ++m) {
      float wa = 0.1f * exp2f((float)(K - 1 - m) * l09) + (m == 0 ? w0fold : 0.f);
      a0 += wa * Hn[(size_t)idx_s[m] * DIMS + t];
    }
    float acc = ((a0 + a1) + (a2 + a3)) + ((a4 + a5) + (a6 + a7));
    float base_v = fresh ? 0.f : exp2f((float)K * l09) * mbank0[(size_t)c * DIMS + t];
    out = acc + base_v;
  }
  mbank_out[(size_t)c * DIMS + t] = out;
  float vv = out * out;
#pragma unroll
  for (int o = 32; o; o >>= 1) vv += __shfl_xor(vv, o);
  if ((t & 63) == 0) red[t >> 6] = vv;
  __syncthreads();
  if (t == 0) msq[c] = (red[0] + red[1]) + (red[2] + red[3]);
}

// ---------------- distances: 32 rows/block, 256 threads -------------------------------------
__global__ __launch_bounds__(256) void dist_kernel(const float* __restrict__ Hn,
                                                   const float* __restrict__ mbank,
                                                   const float* __restrict__ msq,
                                                   float* __restrict__ lscores,
                                                   unsigned short* __restrict__ uf) {
  __shared__ float Ms[NC][260];
  __shared__ float Hs[32][260];
  __shared__ float msq_s[NC];
  int t = threadIdx.x;
  int r0 = blockIdx.x * 32;
  for (int e = t; e < NC * 256; e += 256) {
    int i = e >> 8, d = e & 255;
    Ms[i][d] = mbank[(size_t)i * DIMS + d];
  }
  for (int e = t; e < 32 * 256; e += 256) {
    int i = e >> 8, d = e & 255;
    Hs[i][d] = Hn[(size_t)(r0 + i) * DIMS + d];
  }
  if (t < NC) msq_s[t] = msq[t];
  __syncthreads();
  int r = t >> 3, c0 = (t & 7) * 5;
  float g0 = 0, g1 = 0, g2 = 0, g3 = 0, g4 = 0;
  for (int d = 0; d < DIMS; d += 4) {
    f32x4 f = *(const f32x4*)&Hs[r][d];
    f32x4 m0v = *(const f32x4*)&Ms[c0 + 0][d];
    f32x4 m1v = *(const f32x4*)&Ms[c0 + 1][d];
    f32x4 m2v = *(const f32x4*)&Ms[c0 + 2][d];
    f32x4 m3v = *(const f32x4*)&Ms[c0 + 3][d];
    f32x4 m4v = *(const f32x4*)&Ms[c0 + 4][d];
    g0 += f[0] * m0v[0] + f[1] * m0v[1] + f[2] * m0v[2] + f[3] * m0v[3];
    g1 += f[0] * m1v[0] + f[1] * m1v[1] + f[2] * m1v[2] + f[3] * m1v[3];
    g2 += f[0] * m2v[0] + f[1] * m2v[1] + f[2] * m2v[2] + f[3] * m2v[3];
    g3 += f[0] * m3v[0] + f[1] * m3v[1] + f[2] * m3v[2] + f[3] * m3v[3];
    g4 += f[0] * m4v[0] + f[1] * m4v[1] + f[2] * m4v[2] + f[3] * m4v[3];
  }
  int row = r0 + r;
  float d2[5];
  d2[0] = 1.0f + msq_s[c0 + 0] - 2.0f * g0;
  d2[1] = 1.0f + msq_s[c0 + 1] - 2.0f * g1;
  d2[2] = 1.0f + msq_s[c0 + 2] - 2.0f * g2;
  d2[3] = 1.0f + msq_s[c0 + 3] - 2.0f * g3;
  d2[4] = 1.0f + msq_s[c0 + 4] - 2.0f * g4;
  if (row < BH) {
    float mn = fminf(fminf(fminf(d2[0], d2[1]), fminf(d2[2], d2[3])), d2[4]);
    mn = fminf(mn, __shfl_xor(mn, 1, 8));
    mn = fminf(mn, __shfl_xor(mn, 2, 8));
    mn = fminf(mn, __shfl_xor(mn, 4, 8));
    if ((t & 7) == 0) lscores[row] = sqrtf(fmaxf(mn, 0.0f));
  } else {
    unsigned short* dst = uf + (size_t)(row - BH) * 320 + 256 + c0;
#pragma unroll
    for (int qq = 0; qq < 5; ++qq) dst[qq] = f2b(sqrtf(fmaxf(d2[qq], 0.0f)));
  }
}

// ---------------- final: uscores = relu(bn2(y2)) @ W5 + b5 ----------------------------------
__global__ __launch_bounds__(256) void uscore_bn(const float* __restrict__ y2,
                                                 const float* __restrict__ sums2,
                                                 const float* __restrict__ ssqs2,
                                                 const float* __restrict__ g2,
                                                 const float* __restrict__ be2,
                                                 const float* __restrict__ W5,
                                                 const float* __restrict__ b5,
                                                 float* __restrict__ out) {
  int t = threadIdx.x;
  int wv = t >> 6, lane = t & 63;
  int row = blockIdx.x * 4 + wv;
  float mu = sums2[lane] * (1.0f / 8192.0f);
  float var = ssqs2[lane] * (1.0f / 8192.0f) - mu * mu;
  float sc = g2[lane] * rsqrtf(var + 1e-5f);
  float sh = be2[lane] - mu * sc;
  float v = fmaxf(y2[(size_t)row * 64 + lane] * sc + sh, 0.0f) * W5[lane];
#pragma unroll
  for (int o = 32; o; o >>= 1) v += __shfl_xor(v, o);
  if (lane == 0) out[row] = v + b5[0];
}

extern "C" void kernel_launch(void* const* d_in, const int* in_sizes, int n_in,
                              void* d_out, int out_size, void* d_ws, size_t ws_size,
                              hipStream_t stream) {
  const float* lufeat = (const float*)d_in[0];
  const int* llabel = (const int*)d_in[1];
  const float* W1 = (const float*)d_in[2];
  const float* b1 = (const float*)d_in[3];
  const float* W2 = (const float*)d_in[4];
  const float* b2 = (const float*)d_in[5];
  const float* W3 = (const float*)d_in[6];
  const float* b3 = (const float*)d_in[7];
  const float* W4 = (const float*)d_in[8];
  const float* b4 = (const float*)d_in[9];
  const float* W5 = (const float*)d_in[10];
  const float* b5 = (const float*)d_in[11];
  const float* g1 = (const float*)d_in[12];
  const float* be1 = (const float*)d_in[13];
  const float* g2 = (const float*)d_in[14];
  const float* be2 = (const float*)d_in[15];
  const float* mbank0 = (const float*)d_in[16];
  const float* start0 = (const float*)d_in[17];

  // workspace layout (lifetimes checked — no cross-lifetime aliasing):
  char* ws = (char*)d_ws;
  unsigned short* WeffT = (unsigned short*)(ws + 0);       // [0, 524288)
  float* Hraw = (float*)(ws + 524288);                     // 16384x256 f32
  float* ybuf = (float*)(ws + 524288);                     // lower half of Hraw (dead after dist)
  float* y2 = (float*)(ws + 8912896);                      // upper half of Hraw (dead after dist)
  unsigned short* uf = (unsigned short*)(ws + 17301504);   // 8192x320 bf16
  unsigned short* W3T = (unsigned short*)(ws + 22544384);  // 256x320 bf16
  unsigned short* W4T = (unsigned short*)(ws + 22708224);  // 64x256 bf16
  float* beff = (float*)(ws + 22740992);                   // 256 f32
  float* sums1 = (float*)(ws + 22742016);                  // 256 (zeroed by prep_all)
  float* ssq1 = sums1 + 256;                               // 256
  float* sums2 = ssq1 + 256;                               // 64
  float* ssq2 = sums2 + 64;                                // 64
  float* msq = (float*)(ws + 22744576);                    // 40 f32

  float* lscores = (float*)d_out;
  float* uscores = lscores + 8192;
  float* mbank = uscores + 8192;

  prep_all<<<642, 256, 0, stream>>>(W1, W2, b1, b2, W3, W4, WeffT, beff, W3T, W4T, sums1);
  // main GEMM (A fp32 staged whole, B=WeffT from L2), fused rownorm + uf bf16
  gemm_core<0, 256, 2, 4, 1, 1024><<<512, 256, 0, stream>>>(
      lufeat, 1024, WeffT, beff, Hraw, 256,
      nullptr, nullptr, nullptr, nullptr, nullptr, nullptr, uf);
  bank_kernel<<<NC, 256, 0, stream>>>(llabel, Hraw, mbank0, start0, mbank, msq);
  dist_kernel<<<512, 256, 0, stream>>>(Hraw, mbank, msq, lscores, uf);
  // uf @ W3 + b3 -> ybuf, fused bnstat1
  gemm_core<1, 256, 2, 4, 2, 320><<<256, 256, 0, stream>>>(
      uf, 320, W3T, b3, ybuf, 256,
      sums1, ssq1, nullptr, nullptr, nullptr, nullptr, nullptr);
  // relu(bn1(ybuf)) @ W4 + b4 -> y2, BN1 fused in staging, fused bnstat2
  gemm_core<2, 64, 1, 1, 3, 256><<<128, 256, 0, stream>>>(
      ybuf, 256, W4T, b4, y2, 64,
      sums2, ssq2, sums1, ssq1, g1, be1, nullptr);
  uscore_bn<<<2048, 256, 0, stream>>>(y2, sums2, ssq2, g2, be2, W5, b5, uscores);
}

// Round 11
// 234.249 us; speedup vs baseline: 1.0700x; 1.0700x over previous
//
#include <hip/hip_runtime.h>
#include <hip/hip_bf16.h>
#include <stdint.h>

typedef __attribute__((ext_vector_type(4))) float f32x4;
typedef __attribute__((ext_vector_type(8))) short s16x8;
typedef __attribute__((ext_vector_type(4))) unsigned short u16x4;
typedef __attribute__((ext_vector_type(4))) int i32x4;

#define B2T 16384
#define BH 8192
#define DIN 1024
#define DD1 512
#define DIMS 256
#define NC 40
#define CAPS 2048

__device__ __forceinline__ unsigned short f2b(float f) {
  unsigned int u = __builtin_bit_cast(unsigned int, f);
  u += 0x7FFFu + ((u >> 16) & 1u);
  return (unsigned short)(u >> 16);
}

// ---------------- prep_all: fused Weff tiles / beff / W3T / W4T / stat-zero -----------------
__global__ __launch_bounds__(256) void prep_all(const float* __restrict__ W1,
                                                const float* __restrict__ W2,
                                                const float* __restrict__ b1,
                                                const float* __restrict__ b2,
                                                const float* __restrict__ W3,
                                                const float* __restrict__ W4,
                                                unsigned short* __restrict__ WeffT,
                                                float* __restrict__ beff,
                                                unsigned short* __restrict__ W3T,
                                                unsigned short* __restrict__ W4T,
                                                float* __restrict__ statz) {
  __shared__ float W1s[32][36];
  __shared__ float W2sT[32][36];
  int b = blockIdx.x, t = threadIdx.x;
  if (b < 256) {
    int k0 = (b & 31) * 32, n0 = (b >> 5) * 32;
    int nn = t & 31, kq = t >> 5;  // kq in 0..7
    f32x4 acc = (f32x4){0.f, 0.f, 0.f, 0.f};
    for (int j0 = 0; j0 < DD1; j0 += 32) {
#pragma unroll
      for (int i = 0; i < 4; ++i) {
        int idx = t + 256 * i;
        int kk = idx >> 5, jj = idx & 31;
        W1s[kk][jj] = W1[(size_t)(k0 + kk) * DD1 + j0 + jj];
        W2sT[jj][kk] = W2[(size_t)(j0 + kk) * DIMS + n0 + jj];
      }
      __syncthreads();
#pragma unroll
      for (int jj4 = 0; jj4 < 8; ++jj4) {
        f32x4 w2 = *(const f32x4*)&W2sT[nn][jj4 * 4];
        f32x4 w1_0 = *(const f32x4*)&W1s[kq * 4 + 0][jj4 * 4];
        f32x4 w1_1 = *(const f32x4*)&W1s[kq * 4 + 1][jj4 * 4];
        f32x4 w1_2 = *(const f32x4*)&W1s[kq * 4 + 2][jj4 * 4];
        f32x4 w1_3 = *(const f32x4*)&W1s[kq * 4 + 3][jj4 * 4];
        acc[0] += w1_0[0] * w2[0] + w1_0[1] * w2[1] + w1_0[2] * w2[2] + w1_0[3] * w2[3];
        acc[1] += w1_1[0] * w2[0] + w1_1[1] * w2[1] + w1_1[2] * w2[2] + w1_1[3] * w2[3];
        acc[2] += w1_2[0] * w2[0] + w1_2[1] * w2[1] + w1_2[2] * w2[2] + w1_2[3] * w2[3];
        acc[3] += w1_3[0] * w2[0] + w1_3[1] * w2[1] + w1_3[2] * w2[2] + w1_3[3] * w2[3];
      }
      __syncthreads();
    }
    u16x4 pk = {f2b(acc[0]), f2b(acc[1]), f2b(acc[2]), f2b(acc[3])};
    *(u16x4*)(WeffT + (size_t)(n0 + nn) * DIN + k0 + kq * 4) = pk;
  } else if (b == 256) {
    float a0 = 0.f, a1 = 0.f, a2 = 0.f, a3 = 0.f, a4 = 0.f, a5 = 0.f, a6 = 0.f, a7 = 0.f;
    for (int j = 0; j < DD1; j += 8) {
      a0 += b1[j + 0] * W2[(size_t)(j + 0) * DIMS + t];
      a1 += b1[j + 1] * W2[(size_t)(j + 1) * DIMS + t];
      a2 += b1[j + 2] * W2[(size_t)(j + 2) * DIMS + t];
      a3 += b1[j + 3] * W2[(size_t)(j + 3) * DIMS + t];
      a4 += b1[j + 4] * W2[(size_t)(j + 4) * DIMS + t];
      a5 += b1[j + 5] * W2[(size_t)(j + 5) * DIMS + t];
      a6 += b1[j + 6] * W2[(size_t)(j + 6) * DIMS + t];
      a7 += b1[j + 7] * W2[(size_t)(j + 7) * DIMS + t];
    }
    beff[t] = b2[t] + (((a0 + a1) + (a2 + a3)) + ((a4 + a5) + (a6 + a7)));
  } else if (b < 577) {
    int idx = (b - 257) * 256 + t;
    int n = idx / 320, k = idx - n * 320;
    float v = (k < 296) ? W3[(size_t)k * 256 + n] : 0.0f;
    W3T[(size_t)n * 320 + k] = f2b(v);
  } else if (b < 641) {
    int idx = (b - 577) * 256 + t;
    int n = idx >> 8, k = idx & 255;
    W4T[(size_t)n * 256 + k] = f2b(W4[(size_t)k * 64 + n]);
  } else {
    for (int i = t; i < 640; i += 256) statz[i] = 0.0f;
  }
}

// ---------------- fused bf16 MFMA GEMM core, depth-2 pipeline, TPB-generalized --------------
// AMODE: 0=A fp32, 1=A bf16, 2=A fp32 + BN1 + ReLU (LDS table; K<=256)
// EPI:   1=rownorm+uf-bf16 (CW=4), 2/3=store+bnstat
// Waves NW=TPB/64 arranged as CW col-slices x RG row-groups; AR=RG*MI*16 rows/block.
template <int AMODE, int NB, int MI, int CW, int EPI, int K, int TPB>
__global__ __launch_bounds__(TPB) void gemm_core(
    const void* __restrict__ Aptr, int lda, const unsigned short* __restrict__ BT,
    const float* __restrict__ bias, float* __restrict__ C, int ldc,
    float* __restrict__ sums, float* __restrict__ ssqs,
    const float* __restrict__ bnsum, const float* __restrict__ bnssq,
    const float* __restrict__ bng, const float* __restrict__ bnbe,
    unsigned short* __restrict__ uf) {
  constexpr int NW = TPB / 64;
  constexpr int RG = NW / CW;
  constexpr int AR = RG * MI * 16;        // rows per block
  constexpr int ACH = AR * 8;             // A 16B-units per k-step (8 elems each)
  constexpr int ABN = (ACH + TPB - 1) / TPB;
  constexpr int BBN = NB * 8 / TPB;       // B 16B-units per thread
  __shared__ short A_s[AR][72];
  __shared__ short B_s[NB][72];
  __shared__ float rs[CW][AR];
  __shared__ float bsc_s[(AMODE == 2) ? 256 : 1];
  __shared__ float bsh_s[(AMODE == 2) ? 256 : 1];
  int t = threadIdx.x;
  int m0 = blockIdx.x * AR;
  int w = t >> 6, lane = t & 63, q = lane >> 4, ln = lane & 15;
  f32x4 acc[MI][4];
#pragma unroll
  for (int mi = 0; mi < MI; ++mi)
#pragma unroll
    for (int ni = 0; ni < 4; ++ni) acc[mi][ni] = (f32x4){0.f, 0.f, 0.f, 0.f};

  // two statically-named register buffer sets (never runtime-indexed -> stay in VGPRs)
  f32x4 pa0[ABN][2], pa1[ABN][2];
  s16x8 pab0[ABN], pab1[ABN];
  s16x8 pb0[BBN], pb1[BBN];

  auto issue = [&](int kbase, f32x4 (&paX)[ABN][2], s16x8 (&pabX)[ABN], s16x8 (&pbX)[BBN]) {
    if (ACH >= TPB || t < ACH) {
#pragma unroll
      for (int i = 0; i < ABN; ++i) {
        int ch = t + TPB * i, row = ch >> 3, kp = (ch & 7) * 8;
        if constexpr (AMODE == 1) {
          const unsigned short* A = (const unsigned short*)Aptr;
          pabX[i] = *(const s16x8*)(A + (size_t)(m0 + row) * lda + kbase + kp);
        } else {
          const float* A = (const float*)Aptr;
          const f32x4* src = (const f32x4*)(A + (size_t)(m0 + row) * lda + kbase + kp);
          paX[i][0] = src[0];
          paX[i][1] = src[1];
        }
      }
    }
#pragma unroll
    for (int i = 0; i < BBN; ++i) {
      int ch = t + TPB * i, n = ch >> 3, kp = (ch & 7) * 8;
      pbX[i] = *(const s16x8*)(BT + (size_t)n * K + kbase + kp);
    }
  };

  auto stage = [&](int kk, f32x4 (&paX)[ABN][2], s16x8 (&pabX)[ABN], s16x8 (&pbX)[BBN]) {
    if (ACH >= TPB || t < ACH) {
#pragma unroll
      for (int i = 0; i < ABN; ++i) {
        int ch = t + TPB * i, row = ch >> 3, kp = (ch & 7) * 8;
        if constexpr (AMODE == 1) {
          *(s16x8*)&A_s[row][kp] = pabX[i];
        } else {
          f32x4 v0 = paX[i][0], v1 = paX[i][1];
          if constexpr (AMODE == 2) {
            float vv[8] = {v0[0], v0[1], v0[2], v0[3], v1[0], v1[1], v1[2], v1[3]};
#pragma unroll
            for (int j = 0; j < 8; ++j) {
              int f = kk + kp + j;
              vv[j] = fmaxf(vv[j] * bsc_s[f] + bsh_s[f], 0.0f);
            }
            v0 = (f32x4){vv[0], vv[1], vv[2], vv[3]};
            v1 = (f32x4){vv[4], vv[5], vv[6], vv[7]};
          }
          s16x8 p;
          p[0] = (short)f2b(v0[0]); p[1] = (short)f2b(v0[1]);
          p[2] = (short)f2b(v0[2]); p[3] = (short)f2b(v0[3]);
          p[4] = (short)f2b(v1[0]); p[5] = (short)f2b(v1[1]);
          p[6] = (short)f2b(v1[2]); p[7] = (short)f2b(v1[3]);
          *(s16x8*)&A_s[row][kp] = p;
        }
      }
    }
#pragma unroll
    for (int i = 0; i < BBN; ++i) {
      int ch = t + TPB * i, n = ch >> 3, kp = (ch & 7) * 8;
      *(s16x8*)&B_s[n][kp] = pbX[i];
    }
  };

  auto compute = [&]() {
#pragma unroll
    for (int k32 = 0; k32 < 64; k32 += 32) {
      s16x8 af[MI];
      int ab = (w / CW) * MI * 16;
#pragma unroll
      for (int mi = 0; mi < MI; ++mi)
        af[mi] = *(const s16x8*)&A_s[ab + mi * 16 + ln][k32 + q * 8];
      int nb0 = (w % CW) * 64;
#pragma unroll
      for (int ni = 0; ni < 4; ++ni) {
        s16x8 bfr = *(const s16x8*)&B_s[nb0 + ni * 16 + ln][k32 + q * 8];
#pragma unroll
        for (int mi = 0; mi < MI; ++mi)
          acc[mi][ni] = __builtin_amdgcn_mfma_f32_16x16x32_bf16(af[mi], bfr, acc[mi][ni], 0, 0, 0);
      }
    }
  };

  if constexpr (AMODE == 2) {
    if (t < 256) {
      float mu = bnsum[t] * (1.0f / 8192.0f);
      float var = bnssq[t] * (1.0f / 8192.0f) - mu * mu;
      float sc = bng[t] * rsqrtf(var + 1e-5f);
      bsc_s[t] = sc;
      bsh_s[t] = bnbe[t] - mu * sc;
    }
    __syncthreads();
  }

  const int nst = K >> 6;
  issue(0, pa0, pab0, pb0);
  if (nst > 1) issue(64, pa1, pab1, pb1);

  for (int s = 0; s < nst; s += 2) {
    stage(s << 6, pa0, pab0, pb0);
    __syncthreads();
    if (s + 2 < nst) issue((s + 2) << 6, pa0, pab0, pb0);
    compute();
    __syncthreads();
    if (s + 1 < nst) {
      stage((s + 1) << 6, pa1, pab1, pb1);
      __syncthreads();
      if (s + 3 < nst) issue((s + 3) << 6, pa1, pab1, pb1);
      compute();
      __syncthreads();
    }
  }

  float v[MI][4][4];
#pragma unroll
  for (int mi = 0; mi < MI; ++mi)
#pragma unroll
    for (int ni = 0; ni < 4; ++ni) {
      float bv = bias[(w % CW) * 64 + ni * 16 + ln];
#pragma unroll
      for (int r = 0; r < 4; ++r) v[mi][ni][r] = acc[mi][ni][r] + bv;
    }

  if constexpr (EPI == 1) {
    float p[MI][4];
#pragma unroll
    for (int mi = 0; mi < MI; ++mi)
#pragma unroll
      for (int r = 0; r < 4; ++r) {
        float s = v[mi][0][r] * v[mi][0][r] + v[mi][1][r] * v[mi][1][r] +
                  v[mi][2][r] * v[mi][2][r] + v[mi][3][r] * v[mi][3][r];
        s += __shfl_xor(s, 1); s += __shfl_xor(s, 2);
        s += __shfl_xor(s, 4); s += __shfl_xor(s, 8);
        p[mi][r] = s;
      }
    if (ln == 0) {
#pragma unroll
      for (int mi = 0; mi < MI; ++mi)
#pragma unroll
        for (int r = 0; r < 4; ++r)
          rs[w % CW][(w / CW) * MI * 16 + mi * 16 + q * 4 + r] = p[mi][r];
    }
    __syncthreads();
    if (t < AR) {
      float s = rs[0][t];
#pragma unroll
      for (int i = 1; i < CW; ++i) s += rs[i][t];
      rs[0][t] = rsqrtf(s);
    }
    __syncthreads();
#pragma unroll
    for (int mi = 0; mi < MI; ++mi)
#pragma unroll
      for (int r = 0; r < 4; ++r) {
        int ribf = (w / CW) * MI * 16 + mi * 16 + q * 4 + r;
        float inv = rs[0][ribf];
        int grow = m0 + ribf;
#pragma unroll
        for (int ni = 0; ni < 4; ++ni) {
          int col = (w % CW) * 64 + ni * 16 + ln;
          float nv = v[mi][ni][r] * inv;
          C[(size_t)grow * ldc + col] = nv;
          if (grow >= BH) uf[(size_t)(grow - BH) * 320 + col] = f2b(nv);
        }
      }
  } else {
#pragma unroll
    for (int mi = 0; mi < MI; ++mi)
#pragma unroll
      for (int ni = 0; ni < 4; ++ni)
#pragma unroll
        for (int r = 0; r < 4; ++r) {
          int grow = m0 + (w / CW) * MI * 16 + mi * 16 + q * 4 + r;
          int col = (w % CW) * 64 + ni * 16 + ln;
          C[(size_t)grow * ldc + col] = v[mi][ni][r];
        }
    if constexpr (EPI == 2 || EPI == 3) {
#pragma unroll
      for (int ni = 0; ni < 4; ++ni) {
        float s = 0.f, s2 = 0.f;
#pragma unroll
        for (int mi = 0; mi < MI; ++mi)
#pragma unroll
          for (int r = 0; r < 4; ++r) {
            float x = v[mi][ni][r];
            s += x; s2 += x * x;
          }
        s += __shfl_xor(s, 16); s += __shfl_xor(s, 32);
        s2 += __shfl_xor(s2, 16); s2 += __shfl_xor(s2, 32);
        if (q == 0) {
          int col = (w % CW) * 64 + ni * 16 + ln;
          atomicAdd(&sums[col], s);
          atomicAdd(&ssqs[col], s2);
        }
      }
    }
  }
}

// ---------------- memory-bank EMA scan, closed form (single kernel, 40 blocks) --------------
__global__ __launch_bounds__(256) void bank_kernel(const int* __restrict__ llabel,
                                                   const float* __restrict__ Hn,
                                                   const float* __restrict__ mbank0,
                                                   const float* __restrict__ start0,
                                                   float* __restrict__ mbank_out,
                                                   float* __restrict__ msq) {
  __shared__ i32x4 lab4[BH / 4];  // 32 KB
  __shared__ int idx_s[CAPS];     // 8 KB
  __shared__ int wcnt[4];
  __shared__ float red[4];
  int t = threadIdx.x, c = blockIdx.x;
  int w = t >> 6, lane = t & 63;

  for (int i = t; i < BH / 4; i += 256) lab4[i] = ((const i32x4*)llabel)[i];
  __syncthreads();
  const int* lab_s = (const int*)lab4;

  int base0 = w * (BH / 4);
  int cnt = 0;
  for (int b = 0; b < BH / 4; b += 64)
    cnt += (int)__popcll(__ballot(lab_s[base0 + b + lane] == c));
  if (lane == 0) wcnt[w] = cnt;
  __syncthreads();
  int off = 0;
#pragma unroll
  for (int i = 0; i < 4; ++i)
    if (i < w) off += wcnt[i];
  int Ktot = wcnt[0] + wcnt[1] + wcnt[2] + wcnt[3];

  int running = off;
  for (int b = 0; b < BH / 4; b += 64) {
    bool hit = lab_s[base0 + b + lane] == c;
    unsigned long long mk = __ballot(hit);
    if (hit) {
      int pos = running + (int)__popcll(mk & ((1ull << lane) - 1ull));
      if (pos < CAPS) idx_s[pos] = base0 + b + lane;
    }
    running += (int)__popcll(mk);
  }
  __syncthreads();
  int K = Ktot < CAPS ? Ktot : CAPS;

  const float l09 = -0.15200309344504997f;  // log2(0.9)
  bool fresh = (start0[c] == 0.0f);
  float out;
  if (K == 0) {
    out = mbank0[(size_t)c * DIMS + t];
  } else {
    float a0 = 0.f, a1 = 0.f, a2 = 0.f, a3 = 0.f, a4 = 0.f, a5 = 0.f, a6 = 0.f, a7 = 0.f;
    float w0fold = fresh ? exp2f((float)K * l09) : 0.f;
    int m = 0;
    for (; m + 8 <= K; m += 8) {
      float e = (float)(K - 1 - m);
      float wa = 0.1f * exp2f(e * l09) + (m == 0 ? w0fold : 0.f);
      a0 += wa * Hn[(size_t)idx_s[m + 0] * DIMS + t];
      a1 += 0.1f * exp2f((e - 1.f) * l09) * Hn[(size_t)idx_s[m + 1] * DIMS + t];
      a2 += 0.1f * exp2f((e - 2.f) * l09) * Hn[(size_t)idx_s[m + 2] * DIMS + t];
      a3 += 0.1f * exp2f((e - 3.f) * l09) * Hn[(size_t)idx_s[m + 3] * DIMS + t];
      a4 += 0.1f * exp2f((e - 4.f) * l09) * Hn[(size_t)idx_s[m + 4] * DIMS + t];
      a5 += 0.1f * exp2f((e - 5.f) * l09) * Hn[(size_t)idx_s[m + 5] * DIMS + t];
      a6 += 0.1f * exp2f((e - 6.f) * l09) * Hn[(size_t)idx_s[m + 6] * DIMS + t];
      a7 += 0.1f * exp2f((e - 7.f) * l09) * Hn[(size_t)idx_s[m + 7] * DIMS + t];
    }
    for (; m < K; ++m) {
      float wa = 0.1f * exp2f((float)(K - 1 - m) * l09) + (m == 0 ? w0fold : 0.f);
      a0 += wa * Hn[(size_t)idx_s[m] * DIMS + t];
    }
    float acc = ((a0 + a1) + (a2 + a3)) + ((a4 + a5) + (a6 + a7));
    float base_v = fresh ? 0.f : exp2f((float)K * l09) * mbank0[(size_t)c * DIMS + t];
    out = acc + base_v;
  }
  mbank_out[(size_t)c * DIMS + t] = out;
  float vv = out * out;
#pragma unroll
  for (int o = 32; o; o >>= 1) vv += __shfl_xor(vv, o);
  if ((t & 63) == 0) red[t >> 6] = vv;
  __syncthreads();
  if (t == 0) msq[c] = (red[0] + red[1]) + (red[2] + red[3]);
}

// ---------------- distances: 32 rows/block, 256 threads -------------------------------------
__global__ __launch_bounds__(256) void dist_kernel(const float* __restrict__ Hn,
                                                   const float* __restrict__ mbank,
                                                   const float* __restrict__ msq,
                                                   float* __restrict__ lscores,
                                                   unsigned short* __restrict__ uf) {
  __shared__ float Ms[NC][260];
  __shared__ float Hs[32][260];
  __shared__ float msq_s[NC];
  int t = threadIdx.x;
  int r0 = blockIdx.x * 32;
  for (int e = t; e < NC * 256; e += 256) {
    int i = e >> 8, d = e & 255;
    Ms[i][d] = mbank[(size_t)i * DIMS + d];
  }
  for (int e = t; e < 32 * 256; e += 256) {
    int i = e >> 8, d = e & 255;
    Hs[i][d] = Hn[(size_t)(r0 + i) * DIMS + d];
  }
  if (t < NC) msq_s[t] = msq[t];
  __syncthreads();
  int r = t >> 3, c0 = (t & 7) * 5;
  float g0 = 0, g1 = 0, g2 = 0, g3 = 0, g4 = 0;
  for (int d = 0; d < DIMS; d += 4) {
    f32x4 f = *(const f32x4*)&Hs[r][d];
    f32x4 m0v = *(const f32x4*)&Ms[c0 + 0][d];
    f32x4 m1v = *(const f32x4*)&Ms[c0 + 1][d];
    f32x4 m2v = *(const f32x4*)&Ms[c0 + 2][d];
    f32x4 m3v = *(const f32x4*)&Ms[c0 + 3][d];
    f32x4 m4v = *(const f32x4*)&Ms[c0 + 4][d];
    g0 += f[0] * m0v[0] + f[1] * m0v[1] + f[2] * m0v[2] + f[3] * m0v[3];
    g1 += f[0] * m1v[0] + f[1] * m1v[1] + f[2] * m1v[2] + f[3] * m1v[3];
    g2 += f[0] * m2v[0] + f[1] * m2v[1] + f[2] * m2v[2] + f[3] * m2v[3];
    g3 += f[0] * m3v[0] + f[1] * m3v[1] + f[2] * m3v[2] + f[3] * m3v[3];
    g4 += f[0] * m4v[0] + f[1] * m4v[1] + f[2] * m4v[2] + f[3] * m4v[3];
  }
  int row = r0 + r;
  float d2[5];
  d2[0] = 1.0f + msq_s[c0 + 0] - 2.0f * g0;
  d2[1] = 1.0f + msq_s[c0 + 1] - 2.0f * g1;
  d2[2] = 1.0f + msq_s[c0 + 2] - 2.0f * g2;
  d2[3] = 1.0f + msq_s[c0 + 3] - 2.0f * g3;
  d2[4] = 1.0f + msq_s[c0 + 4] - 2.0f * g4;
  if (row < BH) {
    float mn = fminf(fminf(fminf(d2[0], d2[1]), fminf(d2[2], d2[3])), d2[4]);
    mn = fminf(mn, __shfl_xor(mn, 1, 8));
    mn = fminf(mn, __shfl_xor(mn, 2, 8));
    mn = fminf(mn, __shfl_xor(mn, 4, 8));
    if ((t & 7) == 0) lscores[row] = sqrtf(fmaxf(mn, 0.0f));
  } else {
    unsigned short* dst = uf + (size_t)(row - BH) * 320 + 256 + c0;
#pragma unroll
    for (int qq = 0; qq < 5; ++qq) dst[qq] = f2b(sqrtf(fmaxf(d2[qq], 0.0f)));
  }
}

// ---------------- final: uscores = relu(bn2(y2)) @ W5 + b5 ----------------------------------
__global__ __launch_bounds__(256) void uscore_bn(const float* __restrict__ y2,
                                                 const float* __restrict__ sums2,
                                                 const float* __restrict__ ssqs2,
                                                 const float* __restrict__ g2,
                                                 const float* __restrict__ be2,
                                                 const float* __restrict__ W5,
                                                 const float* __restrict__ b5,
                                                 float* __restrict__ out) {
  int t = threadIdx.x;
  int wv = t >> 6, lane = t & 63;
  int row = blockIdx.x * 4 + wv;
  float mu = sums2[lane] * (1.0f / 8192.0f);
  float var = ssqs2[lane] * (1.0f / 8192.0f) - mu * mu;
  float sc = g2[lane] * rsqrtf(var + 1e-5f);
  float sh = be2[lane] - mu * sc;
  float v = fmaxf(y2[(size_t)row * 64 + lane] * sc + sh, 0.0f) * W5[lane];
#pragma unroll
  for (int o = 32; o; o >>= 1) v += __shfl_xor(v, o);
  if (lane == 0) out[row] = v + b5[0];
}

extern "C" void kernel_launch(void* const* d_in, const int* in_sizes, int n_in,
                              void* d_out, int out_size, void* d_ws, size_t ws_size,
                              hipStream_t stream) {
  const float* lufeat = (const float*)d_in[0];
  const int* llabel = (const int*)d_in[1];
  const float* W1 = (const float*)d_in[2];
  const float* b1 = (const float*)d_in[3];
  const float* W2 = (const float*)d_in[4];
  const float* b2 = (const float*)d_in[5];
  const float* W3 = (const float*)d_in[6];
  const float* b3 = (const float*)d_in[7];
  const float* W4 = (const float*)d_in[8];
  const float* b4 = (const float*)d_in[9];
  const float* W5 = (const float*)d_in[10];
  const float* b5 = (const float*)d_in[11];
  const float* g1 = (const float*)d_in[12];
  const float* be1 = (const float*)d_in[13];
  const float* g2 = (const float*)d_in[14];
  const float* be2 = (const float*)d_in[15];
  const float* mbank0 = (const float*)d_in[16];
  const float* start0 = (const float*)d_in[17];

  // workspace layout (lifetimes checked — no cross-lifetime aliasing):
  char* ws = (char*)d_ws;
  unsigned short* WeffT = (unsigned short*)(ws + 0);       // [0, 524288)
  float* Hraw = (float*)(ws + 524288);                     // 16384x256 f32
  float* ybuf = (float*)(ws + 524288);                     // lower half of Hraw (dead after dist)
  float* y2 = (float*)(ws + 8912896);                      // upper half of Hraw (dead after dist)
  unsigned short* uf = (unsigned short*)(ws + 17301504);   // 8192x320 bf16
  unsigned short* W3T = (unsigned short*)(ws + 22544384);  // 256x320 bf16
  unsigned short* W4T = (unsigned short*)(ws + 22708224);  // 64x256 bf16
  float* beff = (float*)(ws + 22740992);                   // 256 f32
  float* sums1 = (float*)(ws + 22742016);                  // 256 (zeroed by prep_all)
  float* ssq1 = sums1 + 256;                               // 256
  float* sums2 = ssq1 + 256;                               // 64
  float* ssq2 = sums2 + 64;                                // 64
  float* msq = (float*)(ws + 22744576);                    // 40 f32

  float* lscores = (float*)d_out;
  float* uscores = lscores + 8192;
  float* mbank = uscores + 8192;

  prep_all<<<642, 256, 0, stream>>>(W1, W2, b1, b2, W3, W4, WeffT, beff, W3T, W4T, sums1);
  // main GEMM: 512 blocks x 512 threads (8 waves), 32x256 tile -> 16 waves/CU
  gemm_core<0, 256, 1, 4, 1, 1024, 512><<<512, 512, 0, stream>>>(
      lufeat, 1024, WeffT, beff, Hraw, 256,
      nullptr, nullptr, nullptr, nullptr, nullptr, nullptr, uf);
  bank_kernel<<<NC, 256, 0, stream>>>(llabel, Hraw, mbank0, start0, mbank, msq);
  dist_kernel<<<512, 256, 0, stream>>>(Hraw, mbank, msq, lscores, uf);
  // uf @ W3 + b3 -> ybuf, fused bnstat1: 256 blocks x 512 threads
  gemm_core<1, 256, 1, 4, 2, 320, 512><<<256, 512, 0, stream>>>(
      uf, 320, W3T, b3, ybuf, 256,
      sums1, ssq1, nullptr, nullptr, nullptr, nullptr, nullptr);
  // relu(bn1(ybuf)) @ W4 + b4 -> y2, BN1 fused in staging, fused bnstat2
  gemm_core<2, 64, 1, 1, 3, 256, 256><<<128, 256, 0, stream>>>(
      ybuf, 256, W4T, b4, y2, 64,
      sums2, ssq2, sums1, ssq1, g1, be1, nullptr);
  uscore_bn<<<2048, 256, 0, stream>>>(y2, sums2, ssq2, g2, be2, W5, b5, uscores);
}